// Round 2
// baseline (312.454 us; speedup 1.0000x reference)
//
#include <hip/hip_runtime.h>
#include <hip/hip_bf16.h>

#define BB   256
#define II   1152
#define DIN  8
#define OO   10
#define DOUT 16
#define NIB  32
#define CHUNK (II / NIB)   // 36
#define BT   16            // batches per block (4 waves x 4 batches)

// Pass kernel: recomputes x_hat on the fly. All fp32.
// K=0: c uniform 0.1 (softmax of zeros). K>=1: t = dot(V, x_hat), softmax over O.
// s_partial layout: [NIB][B*O*DOUT]
template<int K>
__global__ __launch_bounds__(256) void pass_kernel(
    const float* __restrict__ x,   // fp32 [B][I][DIN]
    const float* __restrict__ w,   // fp32 [O][I][DOUT][DIN]
    const float* __restrict__ V,   // fp32 [B][O][DOUT]
    float* __restrict__ s_partial)
{
  const int tid  = threadIdx.x;
  const int lane = tid & 63;
  const int wave = tid >> 6;
  const int d    = lane & 15;                       // Dout lane
  const int b    = blockIdx.y * BT + wave * 4 + (lane >> 4);
  const int ib   = blockIdx.x;

  float Vreg[OO];
  if (K >= 1) {
#pragma unroll
    for (int o = 0; o < OO; ++o)
      Vreg[o] = V[(b * OO + o) * DOUT + d];
  }
  float s[OO];
#pragma unroll
  for (int o = 0; o < OO; ++o) s[o] = 0.f;

  const int i0 = ib * CHUNK;
  for (int ii = 0; ii < CHUNK; ++ii) {
    const int i = i0 + ii;
    const float4 xa = *(const float4*)(x + (size_t)(b * II + i) * DIN);
    const float4 xb = *(const float4*)(x + (size_t)(b * II + i) * DIN + 4);

    float xh[OO], t[OO];
#pragma unroll
    for (int o = 0; o < OO; ++o) {
      const float* wrow = w + (size_t)((o * II + i) * DOUT + d) * DIN;
      const float4 wa = *(const float4*)(wrow);
      const float4 wb = *(const float4*)(wrow + 4);
      float acc;
      acc  = wa.x * xa.x + wa.y * xa.y + wa.z * xa.z + wa.w * xa.w;
      acc += wb.x * xb.x + wb.y * xb.y + wb.z * xb.z + wb.w * xb.w;
      xh[o] = acc;
      if (K >= 1) {
        float tp = Vreg[o] * acc;          // partial of dot(V[b,o,:], x_hat[b,o,i,:])
        tp += __shfl_xor(tp, 1);
        tp += __shfl_xor(tp, 2);
        tp += __shfl_xor(tp, 4);
        tp += __shfl_xor(tp, 8);
        t[o] = tp;                         // full dot, broadcast to all 16 d-lanes
      }
    }
    if (K == 0) {
#pragma unroll
      for (int o = 0; o < OO; ++o) s[o] += 0.1f * xh[o];
    } else {
      float m = t[0];
#pragma unroll
      for (int o = 1; o < OO; ++o) m = fmaxf(m, t[o]);
      float e[OO];
      float sum = 0.f;
#pragma unroll
      for (int o = 0; o < OO; ++o) { e[o] = __expf(t[o] - m); sum += e[o]; }
      const float inv = 1.0f / sum;
#pragma unroll
      for (int o = 0; o < OO; ++o) s[o] += (e[o] * inv) * xh[o];
    }
  }

  float* sp = s_partial + (size_t)ib * (BB * OO * DOUT);
#pragma unroll
  for (int o = 0; o < OO; ++o)
    sp[(b * OO + o) * DOUT + d] = s[o];
}

// Combine partials over NIB i-blocks, squash, update V / write final output.
template<int K>
__global__ __launch_bounds__(256) void reduce_kernel(
    const float* __restrict__ s_partial,   // [NIB][B*O*DOUT]
    float* __restrict__ V,                 // [B*O*DOUT]
    float* __restrict__ out)               // fp32 [B*O*DOUT]
{
  const int idx = blockIdx.x * 256 + threadIdx.x;    // over B*O*DOUT = 40960
  float s = 0.f;
#pragma unroll
  for (int ib = 0; ib < NIB; ++ib)
    s += s_partial[(size_t)ib * (BB * OO * DOUT) + idx];

  // squash over the 16 Dout lanes (contiguous 16-lane groups share (b,o))
  float sq = s * s;
  sq += __shfl_xor(sq, 1);
  sq += __shfl_xor(sq, 2);
  sq += __shfl_xor(sq, 4);
  sq += __shfl_xor(sq, 8);
  const float mag = sqrtf(sq);
  const float v = sq / (1.f + sq) * (s / (mag + 1e-8f));

  if (K == 0)      V[idx] = v;
  else if (K == 1) V[idx] += v;
  else             out[idx] = v;
}

extern "C" void kernel_launch(void* const* d_in, const int* in_sizes, int n_in,
                              void* d_out, int out_size, void* d_ws, size_t ws_size,
                              hipStream_t stream) {
  const float* x = (const float*)d_in[0];   // fp32 [256,1152,8]
  const float* w = (const float*)d_in[1];   // fp32 [10,1152,16,8]
  float* out = (float*)d_out;               // fp32 [256,10,16]

  float* s_partial = (float*)d_ws;                             // NIB*B*O*DOUT floats
  float* V = s_partial + (size_t)NIB * BB * OO * DOUT;         // B*O*DOUT floats

  dim3 pg(NIB, BB / BT);          // 32 x 16 = 512 blocks
  const int rg = (BB * OO * DOUT) / 256;   // 160 blocks

  pass_kernel<0><<<pg, 256, 0, stream>>>(x, w, V, s_partial);
  reduce_kernel<0><<<rg, 256, 0, stream>>>(s_partial, V, out);
  pass_kernel<1><<<pg, 256, 0, stream>>>(x, w, V, s_partial);
  reduce_kernel<1><<<rg, 256, 0, stream>>>(s_partial, V, out);
  pass_kernel<2><<<pg, 256, 0, stream>>>(x, w, V, s_partial);
  reduce_kernel<2><<<rg, 256, 0, stream>>>(s_partial, V, out);
}

// Round 3
// 247.132 us; speedup vs baseline: 1.2643x; 1.2643x over previous
//
#include <hip/hip_runtime.h>
#include <hip/hip_bf16.h>

#define BB   256
#define II   1152
#define DIN  8
#define OO   10
#define DOUT 16
#define NIB  32
#define CHUNK (II / NIB)   // 36 (divisible by 4)

// Pass kernel: recomputes x_hat on the fly. All fp32.
// One wave = one batch; lane = isub*16 + d (4 i-sublanes x 16 Dout lanes).
// K=0: c uniform 0.1 (softmax of zeros). K>=1: t = dot(V, x_hat), softmax over O.
// s_partial layout: [NIB][B*O*DOUT]
template<int K>
__global__ __launch_bounds__(256) void pass_kernel(
    const float* __restrict__ x,   // fp32 [B][I][DIN]
    const float* __restrict__ w,   // fp32 [O][I][DOUT][DIN]
    const float* __restrict__ V,   // fp32 [B][O][DOUT]
    float* __restrict__ s_partial)
{
  const int tid  = threadIdx.x;
  const int lane = tid & 63;
  const int wave = tid >> 6;
  const int d    = lane & 15;          // Dout lane
  const int isub = lane >> 4;          // 0..3: i-sublane
  const int b    = blockIdx.y * 4 + wave;
  const int ib   = blockIdx.x;

  float Vreg[OO];
  if (K >= 1) {
#pragma unroll
    for (int o = 0; o < OO; ++o)
      Vreg[o] = V[(b * OO + o) * DOUT + d];
  }
  float s[OO];
#pragma unroll
  for (int o = 0; o < OO; ++o) s[o] = 0.f;

  const int i0 = ib * CHUNK;
  for (int ii = 0; ii < CHUNK / 4; ++ii) {     // 9 iterations
    const int i = i0 + ii * 4 + isub;
    const float* xrow = x + (size_t)(b * II + i) * DIN;
    const float4 xa = *(const float4*)(xrow);
    const float4 xb = *(const float4*)(xrow + 4);

    float xh[OO], t[OO];
#pragma unroll
    for (int o = 0; o < OO; ++o) {
      const float* wrow = w + (size_t)((o * II + i) * DOUT + d) * DIN;
      const float4 wa = *(const float4*)(wrow);
      const float4 wb = *(const float4*)(wrow + 4);
      float acc;
      acc  = wa.x * xa.x + wa.y * xa.y + wa.z * xa.z + wa.w * xa.w;
      acc += wb.x * xb.x + wb.y * xb.y + wb.z * xb.z + wb.w * xb.w;
      xh[o] = acc;
      if (K >= 1) {
        float tp = Vreg[o] * acc;      // partial of dot(V[b,o,:], x_hat[b,o,i,:])
        tp += __shfl_xor(tp, 1);
        tp += __shfl_xor(tp, 2);
        tp += __shfl_xor(tp, 4);
        tp += __shfl_xor(tp, 8);
        t[o] = tp;                     // full dot, broadcast within 16-lane group
      }
    }
    if (K == 0) {
#pragma unroll
      for (int o = 0; o < OO; ++o) s[o] += 0.1f * xh[o];
    } else {
      float m = t[0];
#pragma unroll
      for (int o = 1; o < OO; ++o) m = fmaxf(m, t[o]);
      float e[OO];
      float sum = 0.f;
#pragma unroll
      for (int o = 0; o < OO; ++o) { e[o] = __expf(t[o] - m); sum += e[o]; }
      const float inv = 1.0f / sum;
#pragma unroll
      for (int o = 0; o < OO; ++o) s[o] += (e[o] * inv) * xh[o];
    }
  }

  // combine the 4 i-sublane groups
#pragma unroll
  for (int o = 0; o < OO; ++o) {
    s[o] += __shfl_xor(s[o], 16);
    s[o] += __shfl_xor(s[o], 32);
  }

  if (lane < 16) {
    float* sp = s_partial + (size_t)ib * (BB * OO * DOUT);
#pragma unroll
    for (int o = 0; o < OO; ++o)
      sp[(b * OO + o) * DOUT + d] = s[o];
  }
}

// Combine partials over NIB i-blocks, squash, update V / write final output.
template<int K>
__global__ __launch_bounds__(256) void reduce_kernel(
    const float* __restrict__ s_partial,   // [NIB][B*O*DOUT]
    float* __restrict__ V,                 // [B*O*DOUT]
    float* __restrict__ out)               // fp32 [B*O*DOUT]
{
  const int idx = blockIdx.x * 256 + threadIdx.x;    // over B*O*DOUT = 40960
  float s = 0.f;
#pragma unroll
  for (int ib = 0; ib < NIB; ++ib)
    s += s_partial[(size_t)ib * (BB * OO * DOUT) + idx];

  // squash over the 16 Dout lanes (contiguous 16-lane groups share (b,o))
  float sq = s * s;
  sq += __shfl_xor(sq, 1);
  sq += __shfl_xor(sq, 2);
  sq += __shfl_xor(sq, 4);
  sq += __shfl_xor(sq, 8);
  const float mag = sqrtf(sq);
  const float v = sq / (1.f + sq) * (s / (mag + 1e-8f));

  if (K == 0)      V[idx] = v;
  else if (K == 1) V[idx] += v;
  else             out[idx] = v;
}

extern "C" void kernel_launch(void* const* d_in, const int* in_sizes, int n_in,
                              void* d_out, int out_size, void* d_ws, size_t ws_size,
                              hipStream_t stream) {
  const float* x = (const float*)d_in[0];   // fp32 [256,1152,8]
  const float* w = (const float*)d_in[1];   // fp32 [10,1152,16,8]
  float* out = (float*)d_out;               // fp32 [256,10,16]

  float* s_partial = (float*)d_ws;                             // NIB*B*O*DOUT floats
  float* V = s_partial + (size_t)NIB * BB * OO * DOUT;         // B*O*DOUT floats

  dim3 pg(NIB, BB / 4);           // 32 x 64 = 2048 blocks (1 batch per wave)
  const int rg = (BB * OO * DOUT) / 256;   // 160 blocks

  pass_kernel<0><<<pg, 256, 0, stream>>>(x, w, V, s_partial);
  reduce_kernel<0><<<rg, 256, 0, stream>>>(s_partial, V, out);
  pass_kernel<1><<<pg, 256, 0, stream>>>(x, w, V, s_partial);
  reduce_kernel<1><<<rg, 256, 0, stream>>>(s_partial, V, out);
  pass_kernel<2><<<pg, 256, 0, stream>>>(x, w, V, s_partial);
  reduce_kernel<2><<<rg, 256, 0, stream>>>(s_partial, V, out);
}

// Round 4
// 232.722 us; speedup vs baseline: 1.3426x; 1.0619x over previous
//
#include <hip/hip_runtime.h>
#include <hip/hip_bf16.h>

#define BB   256
#define II   1152
#define DIN  8
#define OO   10
#define DOUT 16
#define NIB  32
#define CHUNK (II / NIB)   // 36 (divisible by 2)

// Pass kernel: recomputes x_hat on the fly. All fp32.
// Wave layout: lane = bsub*32 + isub*16 + d  (2 batches x 2 i-sublanes x 16 Dout).
// Each wave handles 2 batches over CHUNK/2 = 18 iterations (w reads amortized 2x).
// K=0: c uniform 0.1 (softmax of zeros). K>=1: t = dot(V, x_hat), softmax over O.
// No max-subtract in softmax: |t| <= |V||x_hat| < 1, exp cannot overflow.
// s_partial layout: [NIB][B*O*DOUT]
template<int K>
__global__ __launch_bounds__(256) void pass_kernel(
    const float* __restrict__ x,   // fp32 [B][I][DIN]
    const float* __restrict__ w,   // fp32 [O][I][DOUT][DIN]
    const float* __restrict__ V,   // fp32 [B][O][DOUT]
    float* __restrict__ s_partial)
{
  const int tid  = threadIdx.x;
  const int lane = tid & 63;
  const int wave = tid >> 6;
  const int d    = lane & 15;          // Dout lane
  const int isub = (lane >> 4) & 1;    // i-sublane
  const int bsub = lane >> 5;          // batch sublane
  const int b    = blockIdx.y * 8 + wave * 2 + bsub;
  const int ib   = blockIdx.x;

  float Vreg[OO];
  if (K >= 1) {
#pragma unroll
    for (int o = 0; o < OO; ++o)
      Vreg[o] = V[(b * OO + o) * DOUT + d];
  }
  float s[OO];
#pragma unroll
  for (int o = 0; o < OO; ++o) s[o] = 0.f;

  const int i0 = ib * CHUNK;
  for (int ii = 0; ii < CHUNK / 2; ++ii) {     // 18 iterations
    const int i = i0 + ii * 2 + isub;
    const float* xrow = x + (size_t)(b * II + i) * DIN;
    const float4 xa = *(const float4*)(xrow);
    const float4 xb = *(const float4*)(xrow + 4);

    float xh[OO], t[OO];
#pragma unroll
    for (int o = 0; o < OO; ++o) {
      const float* wrow = w + (size_t)((o * II + i) * DOUT + d) * DIN;
      const float4 wa = *(const float4*)(wrow);
      const float4 wb = *(const float4*)(wrow + 4);
      float acc;
      acc  = wa.x * xa.x + wa.y * xa.y + wa.z * xa.z + wa.w * xa.w;
      acc += wb.x * xb.x + wb.y * xb.y + wb.z * xb.z + wb.w * xb.w;
      xh[o] = acc;
      if (K >= 1) {
        float tp = Vreg[o] * acc;      // partial of dot(V[b,o,:], x_hat[b,o,i,:])
        tp += __shfl_xor(tp, 1);
        tp += __shfl_xor(tp, 2);
        tp += __shfl_xor(tp, 4);
        tp += __shfl_xor(tp, 8);
        t[o] = tp;                     // full dot, broadcast within 16-lane group
      }
    }
    if (K == 0) {
#pragma unroll
      for (int o = 0; o < OO; ++o) s[o] += 0.1f * xh[o];
    } else {
      float e[OO];
      float sum = 0.f;
#pragma unroll
      for (int o = 0; o < OO; ++o) { e[o] = __expf(t[o]); sum += e[o]; }
      const float inv = __builtin_amdgcn_rcpf(sum);   // 1-ulp rcp, fine vs 2% tol
#pragma unroll
      for (int o = 0; o < OO; ++o) s[o] += (e[o] * inv) * xh[o];
    }
  }

  // combine the 2 i-sublane groups (lane ^ 16 shares (bsub, d))
#pragma unroll
  for (int o = 0; o < OO; ++o)
    s[o] += __shfl_xor(s[o], 16);

  if ((lane & 16) == 0) {              // 32 lanes: 2 bsub x 16 d
    float* sp = s_partial + (size_t)ib * (BB * OO * DOUT);
#pragma unroll
    for (int o = 0; o < OO; ++o)
      sp[(b * OO + o) * DOUT + d] = s[o];
  }
}

// Combine partials over NIB i-blocks, squash, update V / write final output.
template<int K>
__global__ __launch_bounds__(256) void reduce_kernel(
    const float* __restrict__ s_partial,   // [NIB][B*O*DOUT]
    float* __restrict__ V,                 // [B*O*DOUT]
    float* __restrict__ out)               // fp32 [B*O*DOUT]
{
  const int idx = blockIdx.x * 256 + threadIdx.x;    // over B*O*DOUT = 40960
  float s = 0.f;
#pragma unroll
  for (int ib = 0; ib < NIB; ++ib)
    s += s_partial[(size_t)ib * (BB * OO * DOUT) + idx];

  // squash over the 16 Dout lanes (contiguous 16-lane groups share (b,o))
  float sq = s * s;
  sq += __shfl_xor(sq, 1);
  sq += __shfl_xor(sq, 2);
  sq += __shfl_xor(sq, 4);
  sq += __shfl_xor(sq, 8);
  const float mag = sqrtf(sq);
  const float v = sq / (1.f + sq) * (s / (mag + 1e-8f));

  if (K == 0)      V[idx] = v;
  else if (K == 1) V[idx] += v;
  else             out[idx] = v;
}

extern "C" void kernel_launch(void* const* d_in, const int* in_sizes, int n_in,
                              void* d_out, int out_size, void* d_ws, size_t ws_size,
                              hipStream_t stream) {
  const float* x = (const float*)d_in[0];   // fp32 [256,1152,8]
  const float* w = (const float*)d_in[1];   // fp32 [10,1152,16,8]
  float* out = (float*)d_out;               // fp32 [256,10,16]

  float* s_partial = (float*)d_ws;                             // NIB*B*O*DOUT floats
  float* V = s_partial + (size_t)NIB * BB * OO * DOUT;         // B*O*DOUT floats

  dim3 pg(NIB, BB / 8);           // 32 x 32 = 1024 blocks (2 batches per wave)
  const int rg = (BB * OO * DOUT) / 256;   // 160 blocks

  pass_kernel<0><<<pg, 256, 0, stream>>>(x, w, V, s_partial);
  reduce_kernel<0><<<rg, 256, 0, stream>>>(s_partial, V, out);
  pass_kernel<1><<<pg, 256, 0, stream>>>(x, w, V, s_partial);
  reduce_kernel<1><<<rg, 256, 0, stream>>>(s_partial, V, out);
  pass_kernel<2><<<pg, 256, 0, stream>>>(x, w, V, s_partial);
  reduce_kernel<2><<<rg, 256, 0, stream>>>(s_partial, V, out);
}